// Round 9
// baseline (348.903 us; speedup 1.0000x reference)
//
#include <hip/hip_runtime.h>
#include <hip/hip_bf16.h>

// Dims fixed by the reference
#define BB 8
#define NN 2048
#define DF 256
#define HH 64

using bf16x8 = __attribute__((ext_vector_type(8))) short;
using f32x4  = __attribute__((ext_vector_type(4))) float;
typedef unsigned short u16;

static __device__ __forceinline__ short bf_hi_bits(float v, float* hi_f) {
    __hip_bfloat16 h = __float2bfloat16(v);
    *hi_f = __bfloat162float(h);
    return __builtin_bit_cast(short, h);
}

// ---------------------------------------------------------------------------
// Kernel 0: pre-split W into MFMA B-fragment order, split bf16 (hi,lo).
// Layout: [kc(8)][ct(8)][hi 512 | lo 512] u16. Wsp aliases pi head (rows
// 0-15 of b0's pi): wprep writes, qk reads, attn pass-2 overwrites later.
// ---------------------------------------------------------------------------
__global__ __launch_bounds__(64) void wprep_kernel(
    const float* __restrict__ Wq, const float* __restrict__ Wk,
    u16* __restrict__ Wsp)
{
    const int fid  = blockIdx.x;          // kc*8 + ct
    const int kc   = fid >> 3, ct = fid & 7;
    const int lane = threadIdx.x;
    const float* W = (ct < 4) ? Wq : Wk;
    const int col  = (ct & 3) * 16 + (lane & 15);
    const int krow = kc * 32 + (lane >> 4) * 8;
    bf16x8 hv, lv;
#pragma unroll
    for (int j = 0; j < 8; ++j) {
        float w = W[(size_t)(krow + j) * HH + col];
        float hf, d;
        hv[j] = bf_hi_bits(w, &hf);
        lv[j] = bf_hi_bits(w - hf, &d);
    }
    u16* dst = Wsp + (size_t)fid * 1024 + lane * 8;
    *(bf16x8*)dst         = hv;
    *(bf16x8*)(dst + 512) = lv;
}

// ---------------------------------------------------------------------------
// Kernel 1: Q/K projection (r7 proven version, byte-identical). LDS-staged
// Wsp, double-buffered kc chunks, 256 blocks x 256 thr.
// ---------------------------------------------------------------------------
__global__ __launch_bounds__(256) void qk_mfma_kernel(
    const float* __restrict__ f, const float* __restrict__ log_eps,
    const float* __restrict__ Wq, const float* __restrict__ Wk,
    const u16* __restrict__ Wsp,
    __hip_bfloat16* __restrict__ Qs, __hip_bfloat16* __restrict__ Ks)
{
    __shared__ __align__(16) u16 wbuf[2][8192];   // 2 x 16 KB kc-chunks

    const int tid  = threadIdx.x;
    const int wave = tid >> 6;
    const int lane = tid & 63;
    const int l15  = lane & 15, quad = lane >> 4;
    const int row0 = blockIdx.x * 64 + wave * 16;
    const int b    = (blockIdx.x * 64) >> 11;

    f32x4 acc[8] = {};
    const float* frow = f + (size_t)(row0 + l15) * DF + quad * 8;

    {
        const uint4* src = (const uint4*)(Wsp + tid * 32);
        uint4* dst = (uint4*)&wbuf[0][tid * 32];
#pragma unroll
        for (int i = 0; i < 4; ++i) dst[i] = src[i];
    }
    float4 a0 = *(const float4*)(frow);
    float4 a1 = *(const float4*)(frow + 4);
    __syncthreads();

    for (int kc = 0; kc < 8; ++kc) {
        const int cur = kc & 1;
        uint4 w0, w1, w2, w3;
        float4 na0, na1;
        if (kc < 7) {
            const uint4* src =
                (const uint4*)(Wsp + (size_t)(kc + 1) * 8192 + tid * 32);
            w0 = src[0]; w1 = src[1]; w2 = src[2]; w3 = src[3];
            na0 = *(const float4*)(frow + (kc + 1) * 32);
            na1 = *(const float4*)(frow + (kc + 1) * 32 + 4);
        }
        bf16x8 ah, al;
#pragma unroll
        for (int e = 0; e < 4; ++e) {
            float hf, d;
            float v0 = (&a0.x)[e], v1 = (&a1.x)[e];
            ah[e]     = bf_hi_bits(v0, &hf);
            al[e]     = bf_hi_bits(v0 - hf, &d);
            ah[e + 4] = bf_hi_bits(v1, &hf);
            al[e + 4] = bf_hi_bits(v1 - hf, &d);
        }
#pragma unroll
        for (int ct = 0; ct < 8; ++ct) {
            bf16x8 bh = *(const bf16x8*)&wbuf[cur][ct * 1024 + lane * 8];
            bf16x8 bl = *(const bf16x8*)&wbuf[cur][ct * 1024 + 512 + lane * 8];
            acc[ct] = __builtin_amdgcn_mfma_f32_16x16x32_bf16(ah, bh, acc[ct], 0, 0, 0);
            acc[ct] = __builtin_amdgcn_mfma_f32_16x16x32_bf16(ah, bl, acc[ct], 0, 0, 0);
            acc[ct] = __builtin_amdgcn_mfma_f32_16x16x32_bf16(al, bh, acc[ct], 0, 0, 0);
        }
        if (kc < 7) {
            uint4* dst = (uint4*)&wbuf[cur ^ 1][tid * 32];
            dst[0] = w0; dst[1] = w1; dst[2] = w2; dst[3] = w3;
            a0 = na0; a1 = na1;
        }
        __syncthreads();
    }

    const float le = log_eps[b];
#pragma unroll
    for (int ct = 0; ct < 8; ++ct) {
        const int h = (ct & 3) * 16 + l15;
        const float wlast = (ct < 4 ? Wq : Wk)[DF * HH + h];
        __hip_bfloat16* out = (ct < 4) ? Qs : Ks;
        const float sc = (ct < 4) ? 0.125f : 1.0f;
#pragma unroll
        for (int r = 0; r < 4; ++r) {
            int bn = row0 + quad * 4 + r;
            float v = (acc[ct][r] + le * wlast) * sc;
            __hip_bfloat16 hi = __float2bfloat16(v);
            __hip_bfloat16 lo = __float2bfloat16(v - __bfloat162float(hi));
            out[(size_t)bn * 128 + h]      = hi;
            out[(size_t)bn * 128 + 64 + h] = lo;
        }
    }
}

// ---------------------------------------------------------------------------
// Kernel 2: fused attention v5 — r4's proven 2-pass structure widened to
// 128-col strips. Rationale (3-point traffic fit r0/r2/r8): attn time =
// Q-fragment re-read bytes / ~6.4 TB/s, invariant to occupancy. Width 64->128
// halves re-reads: 2 passes x 16 strips x 512 KB x 8 b = 128 MB (+8 MB K).
// K fragments for all 8 ct stay in registers (~128 VGPR). 1024-thread
// blocks (16 waves), grid 128 (1-D, b = bid&7). Only 128/256 CUs occupied —
// irrelevant if the wall is shared bandwidth (it never scaled with blocks).
// ---------------------------------------------------------------------------
__global__ __launch_bounds__(1024) void attn_kernel(
    const u16* __restrict__ Qs, const u16* __restrict__ Ks,
    const float* __restrict__ x, float* __restrict__ y, float* __restrict__ pi)
{
    __shared__ float xs[NN * 3];             // 24 KB: x for this batch
    __shared__ float cred[128];              // strip colsums
    __shared__ float yred[16 * 8 * 16 * 3];  // [wave][ct][col16][d], 24 KB

    const int tid   = threadIdx.x;
    const int bid   = blockIdx.x;
    const int b     = bid & 7;               // XCD affinity
    const int strip = bid >> 3;              // 0..15
    const int m0    = strip * 128;
    const int wave  = tid >> 6;              // 0..15
    const int lane  = tid & 63;
    const int l15   = lane & 15;
    const int quad  = lane >> 4;

    if (tid < 128) cred[tid] = 0.f;
    for (int i = tid; i < NN * 3; i += 1024) xs[i] = x[(size_t)b * NN * 3 + i];
    __syncthreads();

    // K-strip B-fragments: all 8 col-tiles resident (~128 VGPR)
    bf16x8 bh[8][2], bl[8][2];
    {
        const u16* Kb = Ks + ((size_t)b * NN + m0) * 128;
#pragma unroll
        for (int ct = 0; ct < 8; ++ct) {
            const u16* kr = Kb + (size_t)(ct * 16 + l15) * 128;
#pragma unroll
            for (int ks = 0; ks < 2; ++ks) {
                int k0 = ks * 32 + quad * 8;
                bh[ct][ks] = *(const bf16x8*)(kr + k0);
                bl[ct][ks] = *(const bf16x8*)(kr + 64 + k0);
            }
        }
    }

    const u16* Qb = Qs + (size_t)b * NN * 128;
    float cs[8] = {};
    float yacc[8][3] = {};

    // ---- Pass 1: column sums + y accumulation ----
    // wave w owns rows {rt*256 + w*16 .. +16} for rt in [0,8): 128 rows/wave
    for (int rt = 0; rt < 8; ++rt) {
        const int row0 = rt * 256 + wave * 16;
        const u16* qr = Qb + (size_t)(row0 + l15) * 128;
        bf16x8 ah[2], al[2];
#pragma unroll
        for (int ks = 0; ks < 2; ++ks) {
            int k0 = ks * 32 + quad * 8;
            ah[ks] = *(const bf16x8*)(qr + k0);
            al[ks] = *(const bf16x8*)(qr + 64 + k0);
        }
        float xv[4][3];
#pragma unroll
        for (int r = 0; r < 4; ++r) {
            int row = row0 + quad * 4 + r;
            xv[r][0] = xs[row * 3 + 0];
            xv[r][1] = xs[row * 3 + 1];
            xv[r][2] = xs[row * 3 + 2];
        }
#pragma unroll
        for (int ct = 0; ct < 8; ++ct) {
            f32x4 acc = {0.f, 0.f, 0.f, 0.f};
#pragma unroll
            for (int ks = 0; ks < 2; ++ks) {
                acc = __builtin_amdgcn_mfma_f32_16x16x32_bf16(ah[ks], bh[ct][ks], acc, 0, 0, 0);
                acc = __builtin_amdgcn_mfma_f32_16x16x32_bf16(ah[ks], bl[ct][ks], acc, 0, 0, 0);
                acc = __builtin_amdgcn_mfma_f32_16x16x32_bf16(al[ks], bh[ct][ks], acc, 0, 0, 0);
            }
            float s = 0.f;
#pragma unroll
            for (int r = 0; r < 4; ++r) {
                float v = __expf(acc[r]);
                s += v;
                yacc[ct][0] = fmaf(v, xv[r][0], yacc[ct][0]);
                yacc[ct][1] = fmaf(v, xv[r][1], yacc[ct][1]);
                yacc[ct][2] = fmaf(v, xv[r][2], yacc[ct][2]);
            }
            cs[ct] += s;
        }
    }

    // deferred cross-quad reductions, then LDS
#pragma unroll
    for (int ct = 0; ct < 8; ++ct) {
        cs[ct] += __shfl_xor(cs[ct], 16);
        cs[ct] += __shfl_xor(cs[ct], 32);
#pragma unroll
        for (int d = 0; d < 3; ++d) {
            yacc[ct][d] += __shfl_xor(yacc[ct][d], 16);
            yacc[ct][d] += __shfl_xor(yacc[ct][d], 32);
        }
    }
    if (quad == 0) {
#pragma unroll
        for (int ct = 0; ct < 8; ++ct) {
            atomicAdd(&cred[ct * 16 + l15], cs[ct]);
#pragma unroll
            for (int d = 0; d < 3; ++d)
                yred[((wave * 8 + ct) * 16 + l15) * 3 + d] = yacc[ct][d];
        }
    }
    __syncthreads();

    if (tid < 384) {                         // 128 cols x 3 dims
        int c = tid / 3, d = tid - c * 3;
        int ct = c >> 4, cl = c & 15;
        float s = 0.f;
#pragma unroll
        for (int w = 0; w < 16; ++w)
            s += yred[((w * 8 + ct) * 16 + cl) * 3 + d];
        y[((size_t)b * NN + m0 + c) * 3 + d] = s / cred[c];
    }

    const float invN = 1.0f / (float)NN;
    float iv[8];
#pragma unroll
    for (int ct = 0; ct < 8; ++ct) iv[ct] = invN / cred[ct * 16 + l15];
    float* pib = pi + (size_t)b * NN * NN + m0;

    // ---- Pass 2: recompute, write pi (plain stores -> L2 coalesces) ----
    for (int rt = 0; rt < 8; ++rt) {
        const int row0 = rt * 256 + wave * 16;
        const u16* qr = Qb + (size_t)(row0 + l15) * 128;
        bf16x8 ah[2], al[2];
#pragma unroll
        for (int ks = 0; ks < 2; ++ks) {
            int k0 = ks * 32 + quad * 8;
            ah[ks] = *(const bf16x8*)(qr + k0);
            al[ks] = *(const bf16x8*)(qr + 64 + k0);
        }
#pragma unroll
        for (int ct = 0; ct < 8; ++ct) {
            f32x4 acc = {0.f, 0.f, 0.f, 0.f};
#pragma unroll
            for (int ks = 0; ks < 2; ++ks) {
                acc = __builtin_amdgcn_mfma_f32_16x16x32_bf16(ah[ks], bh[ct][ks], acc, 0, 0, 0);
                acc = __builtin_amdgcn_mfma_f32_16x16x32_bf16(ah[ks], bl[ct][ks], acc, 0, 0, 0);
                acc = __builtin_amdgcn_mfma_f32_16x16x32_bf16(al[ks], bh[ct][ks], acc, 0, 0, 0);
            }
            float* op = pib + (size_t)(row0 + quad * 4) * NN + ct * 16 + l15;
#pragma unroll
            for (int r = 0; r < 4; ++r)
                op[(size_t)r * NN] = __expf(acc[r]) * iv[ct];
        }
    }
}

// ---------------------------------------------------------------------------
extern "C" void kernel_launch(void* const* d_in, const int* in_sizes, int n_in,
                              void* d_out, int out_size, void* d_ws, size_t ws_size,
                              hipStream_t stream) {
    const float* f  = (const float*)d_in[0];
    const float* x  = (const float*)d_in[1];
    const float* le = (const float*)d_in[2];
    const float* Wq = (const float*)d_in[3];
    const float* Wk = (const float*)d_in[4];

    float* y  = (float*)d_out;                       // (B, N, 3)
    float* pi = (float*)d_out + (size_t)BB * NN * 3; // (B, N, N)

    // Workspace: exactly the proven 8 MB (split-bf16 Q and K). The 128 KB
    // W-fragment table temporally aliases the pi head (overwritten by attn
    // pass 2, after qk consumed it).
    __hip_bfloat16* Qs = (__hip_bfloat16*)d_ws;      // 4 MB
    __hip_bfloat16* Ks = Qs + (size_t)BB * NN * 128; // 4 MB
    u16* Wsp = (u16*)pi;

    wprep_kernel<<<dim3(64), 64, 0, stream>>>(Wq, Wk, Wsp);
    qk_mfma_kernel<<<dim3(BB * NN / 64), 256, 0, stream>>>(f, le, Wq, Wk, Wsp, Qs, Ks);
    attn_kernel<<<dim3(128), 1024, 0, stream>>>((const u16*)Qs, (const u16*)Ks,
                                                x, y, pi);
}

// Round 10
// 226.503 us; speedup vs baseline: 1.5404x; 1.5404x over previous
//
#include <hip/hip_runtime.h>
#include <hip/hip_bf16.h>

// Dims fixed by the reference
#define BB 8
#define NN 2048
#define DF 256
#define HH 64

using bf16x8 = __attribute__((ext_vector_type(8))) short;
using f32x4  = __attribute__((ext_vector_type(4))) float;
typedef unsigned short u16;

static __device__ __forceinline__ short bf_hi_bits(float v, float* hi_f) {
    __hip_bfloat16 h = __float2bfloat16(v);
    *hi_f = __bfloat162float(h);
    return __builtin_bit_cast(short, h);
}

static __device__ __forceinline__ float bfbits2f(u16 v) {
    unsigned int x = ((unsigned int)v) << 16;
    return __builtin_bit_cast(float, x);
}

// ---------------------------------------------------------------------------
// Kernel 0: pre-split W into MFMA B-fragment order (r7 verbatim).
// ---------------------------------------------------------------------------
__global__ __launch_bounds__(64) void wprep_kernel(
    const float* __restrict__ Wq, const float* __restrict__ Wk,
    u16* __restrict__ Wsp)
{
    const int fid  = blockIdx.x;          // kc*8 + ct
    const int kc   = fid >> 3, ct = fid & 7;
    const int lane = threadIdx.x;
    const float* W = (ct < 4) ? Wq : Wk;
    const int col  = (ct & 3) * 16 + (lane & 15);
    const int krow = kc * 32 + (lane >> 4) * 8;
    bf16x8 hv, lv;
#pragma unroll
    for (int j = 0; j < 8; ++j) {
        float w = W[(size_t)(krow + j) * HH + col];
        float hf, d;
        hv[j] = bf_hi_bits(w, &hf);
        lv[j] = bf_hi_bits(w - hf, &d);
    }
    u16* dst = Wsp + (size_t)fid * 1024 + lane * 8;
    *(bf16x8*)dst         = hv;
    *(bf16x8*)(dst + 512) = lv;
}

// ---------------------------------------------------------------------------
// Kernel 1: Q/K projection (r7 verbatim, proven).
// ---------------------------------------------------------------------------
__global__ __launch_bounds__(256) void qk_mfma_kernel(
    const float* __restrict__ f, const float* __restrict__ log_eps,
    const float* __restrict__ Wq, const float* __restrict__ Wk,
    const u16* __restrict__ Wsp,
    __hip_bfloat16* __restrict__ Qs, __hip_bfloat16* __restrict__ Ks)
{
    __shared__ __align__(16) u16 wbuf[2][8192];

    const int tid  = threadIdx.x;
    const int wave = tid >> 6;
    const int lane = tid & 63;
    const int l15  = lane & 15, quad = lane >> 4;
    const int row0 = blockIdx.x * 64 + wave * 16;
    const int b    = (blockIdx.x * 64) >> 11;

    f32x4 acc[8] = {};
    const float* frow = f + (size_t)(row0 + l15) * DF + quad * 8;

    {
        const uint4* src = (const uint4*)(Wsp + tid * 32);
        uint4* dst = (uint4*)&wbuf[0][tid * 32];
#pragma unroll
        for (int i = 0; i < 4; ++i) dst[i] = src[i];
    }
    float4 a0 = *(const float4*)(frow);
    float4 a1 = *(const float4*)(frow + 4);
    __syncthreads();

    for (int kc = 0; kc < 8; ++kc) {
        const int cur = kc & 1;
        uint4 w0, w1, w2, w3;
        float4 na0, na1;
        if (kc < 7) {
            const uint4* src =
                (const uint4*)(Wsp + (size_t)(kc + 1) * 8192 + tid * 32);
            w0 = src[0]; w1 = src[1]; w2 = src[2]; w3 = src[3];
            na0 = *(const float4*)(frow + (kc + 1) * 32);
            na1 = *(const float4*)(frow + (kc + 1) * 32 + 4);
        }
        bf16x8 ah, al;
#pragma unroll
        for (int e = 0; e < 4; ++e) {
            float hf, d;
            float v0 = (&a0.x)[e], v1 = (&a1.x)[e];
            ah[e]     = bf_hi_bits(v0, &hf);
            al[e]     = bf_hi_bits(v0 - hf, &d);
            ah[e + 4] = bf_hi_bits(v1, &hf);
            al[e + 4] = bf_hi_bits(v1 - hf, &d);
        }
#pragma unroll
        for (int ct = 0; ct < 8; ++ct) {
            bf16x8 bh = *(const bf16x8*)&wbuf[cur][ct * 1024 + lane * 8];
            bf16x8 bl = *(const bf16x8*)&wbuf[cur][ct * 1024 + 512 + lane * 8];
            acc[ct] = __builtin_amdgcn_mfma_f32_16x16x32_bf16(ah, bh, acc[ct], 0, 0, 0);
            acc[ct] = __builtin_amdgcn_mfma_f32_16x16x32_bf16(ah, bl, acc[ct], 0, 0, 0);
            acc[ct] = __builtin_amdgcn_mfma_f32_16x16x32_bf16(al, bh, acc[ct], 0, 0, 0);
        }
        if (kc < 7) {
            uint4* dst = (uint4*)&wbuf[cur ^ 1][tid * 32];
            dst[0] = w0; dst[1] = w1; dst[2] = w2; dst[3] = w3;
            a0 = na0; a1 = na1;
        }
        __syncthreads();
    }

    const float le = log_eps[b];
#pragma unroll
    for (int ct = 0; ct < 8; ++ct) {
        const int h = (ct & 3) * 16 + l15;
        const float wlast = (ct < 4 ? Wq : Wk)[DF * HH + h];
        __hip_bfloat16* out = (ct < 4) ? Qs : Ks;
        const float sc = (ct < 4) ? 0.125f : 1.0f;
#pragma unroll
        for (int r = 0; r < 4; ++r) {
            int bn = row0 + quad * 4 + r;
            float v = (acc[ct][r] + le * wlast) * sc;
            __hip_bfloat16 hi = __float2bfloat16(v);
            __hip_bfloat16 lo = __float2bfloat16(v - __bfloat162float(hi));
            out[(size_t)bn * 128 + h]      = hi;
            out[(size_t)bn * 128 + 64 + h] = lo;
        }
    }
}

// Swizzled LDS Q-tile helpers. Tile = 128 rows x 256 B, XOR-swizzle
// (guide G4: row-major D=128 is a 16-way bank conflict; byte ^= (row&7)<<4
// spreads lanes over 8 slots -> 2-way = free). Offsets in u16 units.
#define QT_SWZ(ROW, OFFU16) (((ROW) * 128) + ((OFFU16) ^ (((ROW) & 7) << 3)))

// ---------------------------------------------------------------------------
// Kernel 2: column sums + y, LDS-shared Q. Grid 128 (16 strips x 8 b,
// b = bid&7 XCD affinity), 512 thr. Block reads Q_b ONCE (16 double-buffered
// 32 KB tiles); each wave owns one 16-col ct (16 VGPR K frags -> no spill,
// the r9 failure mode). cs is exact (full row sweep); y final.
// ---------------------------------------------------------------------------
__global__ __launch_bounds__(512) void colsum_kernel(
    const u16* __restrict__ Qs, const u16* __restrict__ Ks,
    const float* __restrict__ x, float* __restrict__ y,
    float* __restrict__ csbuf)
{
    __shared__ __align__(16) u16 qt[2][16384];   // 2 x 32 KB Q tiles
    __shared__ float xs[NN * 3];                 // 24 KB

    const int tid  = threadIdx.x;
    const int bid  = blockIdx.x;
    const int b    = bid & 7;
    const int m0   = (bid >> 3) * 128;           // strip 0..15
    const int wave = tid >> 6;                   // = ct, 0..7
    const int lane = tid & 63;
    const int l15  = lane & 15;
    const int quad = lane >> 4;
    const int srow = tid >> 2;                   // staging row 0..127
    const int spart = tid & 3;                   // 64 B part

    for (int i = tid; i < NN * 3; i += 512) xs[i] = x[(size_t)b * NN * 3 + i];

    // this wave's K fragment (16 cols)
    bf16x8 bh[2], bl[2];
    {
        const u16* kr = Ks + ((size_t)b * NN + m0 + wave * 16 + l15) * 128;
#pragma unroll
        for (int ks = 0; ks < 2; ++ks) {
            int k0 = ks * 32 + quad * 8;
            bh[ks] = *(const bf16x8*)(kr + k0);
            bl[ks] = *(const bf16x8*)(kr + 64 + k0);
        }
    }

    const u16* Qb = Qs + (size_t)b * NN * 128;

    // stage tile 0
    {
        const uint4* src = (const uint4*)(Qb + (size_t)srow * 128 + spart * 32);
#pragma unroll
        for (int i = 0; i < 4; ++i)
            *(uint4*)&qt[0][QT_SWZ(srow, spart * 32 + i * 8)] = src[i];
    }
    __syncthreads();

    float cs = 0.f, ya0 = 0.f, ya1 = 0.f, ya2 = 0.f;

    for (int tile = 0; tile < 16; ++tile) {
        const int cur = tile & 1;
        uint4 nw0, nw1, nw2, nw3;
        if (tile < 15) {
            const uint4* src = (const uint4*)
                (Qb + (size_t)((tile + 1) * 128 + srow) * 128 + spart * 32);
            nw0 = src[0]; nw1 = src[1]; nw2 = src[2]; nw3 = src[3];
        }
#pragma unroll
        for (int sub = 0; sub < 8; ++sub) {
            const int lr = sub * 16 + l15;
            bf16x8 ah[2], al[2];
#pragma unroll
            for (int ks = 0; ks < 2; ++ks) {
                int o = ks * 32 + quad * 8;
                ah[ks] = *(const bf16x8*)&qt[cur][QT_SWZ(lr, o)];
                al[ks] = *(const bf16x8*)&qt[cur][QT_SWZ(lr, o + 64)];
            }
            f32x4 acc = {0.f, 0.f, 0.f, 0.f};
#pragma unroll
            for (int ks = 0; ks < 2; ++ks) {
                acc = __builtin_amdgcn_mfma_f32_16x16x32_bf16(ah[ks], bh[ks], acc, 0, 0, 0);
                acc = __builtin_amdgcn_mfma_f32_16x16x32_bf16(ah[ks], bl[ks], acc, 0, 0, 0);
                acc = __builtin_amdgcn_mfma_f32_16x16x32_bf16(al[ks], bh[ks], acc, 0, 0, 0);
            }
#pragma unroll
            for (int r = 0; r < 4; ++r) {
                float v = __expf(acc[r]);
                int row = tile * 128 + sub * 16 + quad * 4 + r;
                cs += v;
                ya0 = fmaf(v, xs[row * 3 + 0], ya0);
                ya1 = fmaf(v, xs[row * 3 + 1], ya1);
                ya2 = fmaf(v, xs[row * 3 + 2], ya2);
            }
        }
        if (tile < 15) {
            u16* dst = &qt[cur ^ 1][0];
            *(uint4*)&dst[QT_SWZ(srow, spart * 32 + 0)]  = nw0;
            *(uint4*)&dst[QT_SWZ(srow, spart * 32 + 8)]  = nw1;
            *(uint4*)&dst[QT_SWZ(srow, spart * 32 + 16)] = nw2;
            *(uint4*)&dst[QT_SWZ(srow, spart * 32 + 24)] = nw3;
        }
        __syncthreads();
    }

    // reduce over quads (rows) — cols are wave-private, no LDS needed
    cs  += __shfl_xor(cs, 16);  cs  += __shfl_xor(cs, 32);
    ya0 += __shfl_xor(ya0, 16); ya0 += __shfl_xor(ya0, 32);
    ya1 += __shfl_xor(ya1, 16); ya1 += __shfl_xor(ya1, 32);
    ya2 += __shfl_xor(ya2, 16); ya2 += __shfl_xor(ya2, 32);

    if (quad == 0) {
        const int col = m0 + wave * 16 + l15;
        csbuf[(size_t)b * NN + col] = cs;
        const float inv = 1.0f / cs;
        float* yp = y + ((size_t)b * NN + col) * 3;
        yp[0] = ya0 * inv;
        yp[1] = ya1 * inv;
        yp[2] = ya2 * inv;
    }
}

// ---------------------------------------------------------------------------
// Kernel 3: pi writer, same LDS-Q skeleton. Grid 256 (16 strips x 2 row-
// chunks x 8 b). Reads cs from the pi head; skips b0 rows 0-7 (cs region,
// r8's proven guard) — cleanup fills them after.
// ---------------------------------------------------------------------------
__global__ __launch_bounds__(512) void pi_kernel(
    const u16* __restrict__ Qs, const u16* __restrict__ Ks,
    const float* __restrict__ csbuf, float* __restrict__ pi)
{
    __shared__ __align__(16) u16 qt[2][16384];   // 2 x 32 KB Q tiles

    const int tid   = threadIdx.x;
    const int bid   = blockIdx.x;
    const int b     = bid & 7;
    const int t     = bid >> 3;                  // 0..31
    const int chunk = t & 1;                     // 1024-row chunk
    const int m0    = (t >> 1) * 128;            // strip 0..15
    const int wave  = tid >> 6;                  // = ct
    const int lane  = tid & 63;
    const int l15   = lane & 15;
    const int quad  = lane >> 4;
    const int srow  = tid >> 2;
    const int spart = tid & 3;
    const int rbase = chunk * 1024;

    const int col = m0 + wave * 16 + l15;
    const float iv = (1.0f / (float)NN) / csbuf[(size_t)b * NN + col];

    bf16x8 bh[2], bl[2];
    {
        const u16* kr = Ks + ((size_t)b * NN + col) * 128;
#pragma unroll
        for (int ks = 0; ks < 2; ++ks) {
            int k0 = ks * 32 + quad * 8;
            bh[ks] = *(const bf16x8*)(kr + k0);
            bl[ks] = *(const bf16x8*)(kr + 64 + k0);
        }
    }

    const u16* Qb = Qs + (size_t)b * NN * 128;
    float* pib = pi + (size_t)b * NN * NN;

    {
        const uint4* src =
            (const uint4*)(Qb + (size_t)(rbase + srow) * 128 + spart * 32);
#pragma unroll
        for (int i = 0; i < 4; ++i)
            *(uint4*)&qt[0][QT_SWZ(srow, spart * 32 + i * 8)] = src[i];
    }
    __syncthreads();

    for (int tile = 0; tile < 8; ++tile) {
        const int cur = tile & 1;
        uint4 nw0, nw1, nw2, nw3;
        if (tile < 7) {
            const uint4* src = (const uint4*)
                (Qb + (size_t)(rbase + (tile + 1) * 128 + srow) * 128 + spart * 32);
            nw0 = src[0]; nw1 = src[1]; nw2 = src[2]; nw3 = src[3];
        }
#pragma unroll
        for (int sub = 0; sub < 8; ++sub) {
            const int lr = sub * 16 + l15;
            bf16x8 ah[2], al[2];
#pragma unroll
            for (int ks = 0; ks < 2; ++ks) {
                int o = ks * 32 + quad * 8;
                ah[ks] = *(const bf16x8*)&qt[cur][QT_SWZ(lr, o)];
                al[ks] = *(const bf16x8*)&qt[cur][QT_SWZ(lr, o + 64)];
            }
            f32x4 acc = {0.f, 0.f, 0.f, 0.f};
#pragma unroll
            for (int ks = 0; ks < 2; ++ks) {
                acc = __builtin_amdgcn_mfma_f32_16x16x32_bf16(ah[ks], bh[ks], acc, 0, 0, 0);
                acc = __builtin_amdgcn_mfma_f32_16x16x32_bf16(ah[ks], bl[ks], acc, 0, 0, 0);
                acc = __builtin_amdgcn_mfma_f32_16x16x32_bf16(al[ks], bh[ks], acc, 0, 0, 0);
            }
            const int grow0 = rbase + tile * 128 + sub * 16 + quad * 4;
            // b0 rows 0-7 hold cs until cleanup: skip (r8 proven guard)
            const bool skip = (b == 0) && (chunk == 0) && (tile == 0) &&
                              (sub == 0) && (quad < 2);
            if (!skip) {
                float* op = pib + (size_t)grow0 * NN + col;
#pragma unroll
                for (int r = 0; r < 4; ++r)
                    op[(size_t)r * NN] = __expf(acc[r]) * iv;
            }
        }
        if (tile < 7) {
            u16* dst = &qt[cur ^ 1][0];
            *(uint4*)&dst[QT_SWZ(srow, spart * 32 + 0)]  = nw0;
            *(uint4*)&dst[QT_SWZ(srow, spart * 32 + 8)]  = nw1;
            *(uint4*)&dst[QT_SWZ(srow, spart * 32 + 16)] = nw2;
            *(uint4*)&dst[QT_SWZ(srow, spart * 32 + 24)] = nw3;
        }
        __syncthreads();
    }
}

// ---------------------------------------------------------------------------
// Kernel 4: cleanup (r8 verbatim, proven) — fill pi(b0, rows 0-7).
// ---------------------------------------------------------------------------
__global__ __launch_bounds__(512) void cleanup_kernel(
    const u16* __restrict__ Qs, const u16* __restrict__ Ks,
    float* __restrict__ pi)
{
    __shared__ float csl[256];
    __shared__ u16 ql[8 * 128];

    const int s   = blockIdx.x;              // 0..7: cols s*256..
    const int tid = threadIdx.x;

    if (tid < 256) csl[tid] = pi[s * 256 + tid];
    for (int i = tid; i < 1024; i += 512) ql[i] = Qs[i];
    __syncthreads();

    const float invN = 1.0f / (float)NN;
#pragma unroll
    for (int k = 0; k < 4; ++k) {
        const int idx = tid + k * 512;
        const int row = idx >> 8;
        const int cl  = idx & 255;
        const int col = s * 256 + cl;
        const u16* kk = Ks + (size_t)col * 128;
        float dot = 0.f;
#pragma unroll 8
        for (int h = 0; h < 64; ++h) {
            float qf = bfbits2f(ql[row * 128 + h]) + bfbits2f(ql[row * 128 + 64 + h]);
            float kf = bfbits2f(kk[h]) + bfbits2f(kk[64 + h]);
            dot = fmaf(qf, kf, dot);
        }
        pi[(size_t)row * NN + col] = __expf(dot) * invN / csl[cl];
    }
}

// ---------------------------------------------------------------------------
extern "C" void kernel_launch(void* const* d_in, const int* in_sizes, int n_in,
                              void* d_out, int out_size, void* d_ws, size_t ws_size,
                              hipStream_t stream) {
    const float* f  = (const float*)d_in[0];
    const float* x  = (const float*)d_in[1];
    const float* le = (const float*)d_in[2];
    const float* Wq = (const float*)d_in[3];
    const float* Wk = (const float*)d_in[4];

    float* y  = (float*)d_out;                       // (B, N, 3)
    float* pi = (float*)d_out + (size_t)BB * NN * 3; // (B, N, N)

    // Workspace: exactly the proven 8 MB (split-bf16 Q and K). Scratch
    // aliases the pi head with stream-ordered lifetimes:
    //   wprep -> Wsp (128 KB) -> consumed by qk
    //   colsum -> cs (64 KB, b0 rows 0-7) -> read by pi_kernel,
    //   overwritten last by cleanup_kernel.
    __hip_bfloat16* Qs = (__hip_bfloat16*)d_ws;      // 4 MB
    __hip_bfloat16* Ks = Qs + (size_t)BB * NN * 128; // 4 MB
    u16*   Wsp   = (u16*)pi;
    float* csbuf = pi;

    wprep_kernel<<<dim3(64), 64, 0, stream>>>(Wq, Wk, Wsp);
    qk_mfma_kernel<<<dim3(BB * NN / 64), 256, 0, stream>>>(f, le, Wq, Wk, Wsp, Qs, Ks);
    colsum_kernel<<<dim3(128), 512, 0, stream>>>((const u16*)Qs, (const u16*)Ks,
                                                 x, y, csbuf);
    pi_kernel<<<dim3(256), 512, 0, stream>>>((const u16*)Qs, (const u16*)Ks,
                                             csbuf, pi);
    cleanup_kernel<<<dim3(8), 512, 0, stream>>>((const u16*)Qs, (const u16*)Ks, pi);
}